// Round 10
// baseline (840.872 us; speedup 1.0000x reference)
//
#include <hip/hip_runtime.h>
#include <math.h>

#define IN_C 128
#define OUT_C 64
#define ALPHA 0.2f

#define SCAN_BLOCK 256
#define SCAN_ITEMS 4
#define SCAN_TILE (SCAN_BLOCK * SCAN_ITEMS)  // 1024 elements per block

#define LDK 136  // padded halfwords per LDS row

#define PA_EPT 32               // edges per thread in pass A
#define PA_TILE (256 * PA_EPT)  // 8192 edges per block
#define BSH 8                   // bucket shift: 256 nodes per bucket
#define NPB 256                 // nodes per bucket
#define MAXB 512                // max buckets (n <= 131072)

typedef __attribute__((ext_vector_type(8))) short short8;
typedef __attribute__((ext_vector_type(4))) float v4f;

__device__ __forceinline__ ushort f2b(float f) {  // fp32 -> bf16 RNE
  unsigned u = __float_as_uint(f);
  u += 0x7fffu + ((u >> 16) & 1u);
  return (ushort)(u >> 16);
}
__device__ __forceinline__ float b2f(ushort h) {
  return __uint_as_float(((unsigned)h) << 16);
}
__device__ __forceinline__ float lrelu_exp(float z) {
  return expf(z > 0.f ? z : ALPHA * z);
}

// ---------------------------------------------------------------------------
// Kernel 1: h = bf16(x) @ bf16(W) via MFMA 16x16x32, fp32 accumulate.
// grid ~512 blocks, ~3 tiles each: amortizes W staging + bfrag preload.
// ---------------------------------------------------------------------------
__global__ __launch_bounds__(256) void gemm_st_kernel(
    const float* __restrict__ x, const float* __restrict__ W,
    const float* __restrict__ a, ushort* __restrict__ hb,
    float* __restrict__ s, float* __restrict__ t, int n_nodes, int n_tiles) {
  __shared__ ushort xs[64 * LDK];
  __shared__ ushort ws[64 * LDK];

  const int tid = threadIdx.x;
  const int wave = tid >> 6;
  const int lane = tid & 63;
  const int li = lane & 15;
  const int quad = lane >> 4;

  for (int i = tid; i < IN_C * OUT_C; i += 256) {
    const int k = i >> 6;
    const int n = i & 63;
    ws[n * LDK + k] = f2b(W[i]);
  }
  __syncthreads();

  short8 bfrag[4][4];
#pragma unroll
  for (int ct = 0; ct < 4; ++ct)
#pragma unroll
    for (int kk = 0; kk < 4; ++kk)
      bfrag[ct][kk] =
          *(const short8*)&ws[(ct * 16 + li) * LDK + kk * 32 + quad * 8];

  float a1v[4], a2v[4];
#pragma unroll
  for (int ct = 0; ct < 4; ++ct) {
    a1v[ct] = a[ct * 16 + li];
    a2v[ct] = a[OUT_C + ct * 16 + li];
  }

  for (int tile = blockIdx.x; tile < n_tiles; tile += gridDim.x) {
    const int row0 = tile * 64;

    __syncthreads();
    for (int i = tid; i < 64 * (IN_C / 4); i += 256) {
      const int r = i >> 5;
      const int c4 = i & 31;
      int row = row0 + r;
      row = row < n_nodes ? row : n_nodes - 1;
      const float4 v = *(const float4*)&x[(size_t)row * IN_C + c4 * 4];
      uint2 p;
      p.x = (unsigned)f2b(v.x) | ((unsigned)f2b(v.y) << 16);
      p.y = (unsigned)f2b(v.z) | ((unsigned)f2b(v.w) << 16);
      *(uint2*)&xs[r * LDK + c4 * 4] = p;
    }
    __syncthreads();

    v4f acc[4];
#pragma unroll
    for (int ct = 0; ct < 4; ++ct) acc[ct] = (v4f){0.f, 0.f, 0.f, 0.f};

    const int rbase = wave * 16;
#pragma unroll
    for (int kk = 0; kk < 4; ++kk) {
      const short8 af =
          *(const short8*)&xs[(rbase + li) * LDK + kk * 32 + quad * 8];
#pragma unroll
      for (int ct = 0; ct < 4; ++ct)
        acc[ct] = __builtin_amdgcn_mfma_f32_16x16x32_bf16(af, bfrag[ct][kk],
                                                          acc[ct], 0, 0, 0);
    }

    const int growbase = row0 + rbase + quad * 4;
    float ps[4] = {0.f, 0.f, 0.f, 0.f};
    float pt[4] = {0.f, 0.f, 0.f, 0.f};
#pragma unroll
    for (int ct = 0; ct < 4; ++ct) {
#pragma unroll
      for (int r = 0; r < 4; ++r) {
        const float hv = acc[ct][r];
        ps[r] += hv * a1v[ct];
        pt[r] += hv * a2v[ct];
        const int grow = growbase + r;
        if (grow < n_nodes)
          hb[(size_t)grow * OUT_C + ct * 16 + li] = f2b(hv);
      }
    }
#pragma unroll
    for (int m = 1; m <= 8; m <<= 1) {
#pragma unroll
      for (int r = 0; r < 4; ++r) {
        ps[r] += __shfl_xor(ps[r], m, 64);
        pt[r] += __shfl_xor(pt[r], m, 64);
      }
    }
    if (li < 4) {
      const int grow = growbase + li;
      if (grow < n_nodes) {
        const float sv = li == 0 ? ps[0] : li == 1 ? ps[1] : li == 2 ? ps[2] : ps[3];
        const float tv = li == 0 ? pt[0] : li == 1 ? pt[1] : li == 2 ? pt[2] : pt[3];
        s[grow] = sv;
        t[grow] = tv;
      }
    }
  }
}

// ---------------------------------------------------------------------------
// Pass A1: per-(block,bucket) counts via LDS histogram; int4 edge reads.
// counts_tbl layout: [bucket][block] (bucket-major).
// ---------------------------------------------------------------------------
__global__ __launch_bounds__(256) void pa_count(const int* __restrict__ src,
                                                int* __restrict__ counts_tbl,
                                                int nblk_a, int nbuck, int E) {
  __shared__ int hist[MAXB];
  const int tid = threadIdx.x;
  for (int i = tid; i < MAXB; i += 256) hist[i] = 0;
  __syncthreads();
  const int e0 = blockIdx.x * PA_TILE + tid * PA_EPT;
  if (e0 + PA_EPT <= E) {
#pragma unroll
    for (int i = 0; i < PA_EPT / 4; ++i) {
      const int4 v = *(const int4*)(src + e0 + i * 4);
      atomicAdd(&hist[v.x >> BSH], 1);
      atomicAdd(&hist[v.y >> BSH], 1);
      atomicAdd(&hist[v.z >> BSH], 1);
      atomicAdd(&hist[v.w >> BSH], 1);
    }
  } else {
    for (int e = e0; e < E; ++e) atomicAdd(&hist[src[e] >> BSH], 1);
  }
  __syncthreads();
  for (int b = tid; b < nbuck; b += 256)
    counts_tbl[(size_t)b * nblk_a + blockIdx.x] = hist[b];
}

// ---------------------------------------------------------------------------
// 3-pass device-wide exclusive scan (over the counts table).
// ---------------------------------------------------------------------------
__global__ __launch_bounds__(SCAN_BLOCK) void scan_partial(
    const int* __restrict__ cnt, int* __restrict__ block_sums, int n) {
  const int tid = threadIdx.x;
  const int base = blockIdx.x * SCAN_TILE + tid * SCAN_ITEMS;
  int s = 0;
#pragma unroll
  for (int i = 0; i < SCAN_ITEMS; ++i) {
    const int idx = base + i;
    if (idx < n) s += cnt[idx];
  }
  __shared__ int wsum[SCAN_BLOCK / 64];
#pragma unroll
  for (int off = 32; off; off >>= 1) s += __shfl_down(s, off, 64);
  if ((tid & 63) == 0) wsum[tid >> 6] = s;
  __syncthreads();
  if (tid == 0) {
    int tot = 0;
#pragma unroll
    for (int w = 0; w < SCAN_BLOCK / 64; ++w) tot += wsum[w];
    block_sums[blockIdx.x] = tot;
  }
}

__global__ __launch_bounds__(1024) void scan_blocksums(
    int* __restrict__ block_sums, int nb) {
  __shared__ int sh[1024];
  const int tid = threadIdx.x;
  const int v = (tid < nb) ? block_sums[tid] : 0;
  sh[tid] = v;
  __syncthreads();
  int val = v;
  for (int off = 1; off < 1024; off <<= 1) {
    const int other = (tid >= off) ? sh[tid - off] : 0;
    __syncthreads();
    val += other;
    sh[tid] = val;
    __syncthreads();
  }
  if (tid < nb) block_sums[tid] = val - v;
}

__global__ __launch_bounds__(SCAN_BLOCK) void scan_final_plain(
    const int* __restrict__ cnt, const int* __restrict__ block_sums,
    int* __restrict__ outv, int n) {
  __shared__ int tsum[SCAN_BLOCK];
  const int tid = threadIdx.x;
  const int base = blockIdx.x * SCAN_TILE + tid * SCAN_ITEMS;
  int local[SCAN_ITEMS];
  int s = 0;
#pragma unroll
  for (int i = 0; i < SCAN_ITEMS; ++i) {
    const int idx = base + i;
    local[i] = (idx < n) ? cnt[idx] : 0;
    s += local[i];
  }
  tsum[tid] = s;
  __syncthreads();
  int val = s;
  for (int off = 1; off < SCAN_BLOCK; off <<= 1) {
    const int other = (tid >= off) ? tsum[tid - off] : 0;
    __syncthreads();
    val += other;
    tsum[tid] = val;
    __syncthreads();
  }
  int prefix = block_sums[blockIdx.x] + (val - s);
#pragma unroll
  for (int i = 0; i < SCAN_ITEMS; ++i) {
    const int idx = base + i;
    if (idx < n) {
      outv[idx] = prefix;
      prefix += local[i];
    }
  }
}

// ---------------------------------------------------------------------------
// Pass A2: scatter edges into bucket regions as packed (src,dst) int2.
// ---------------------------------------------------------------------------
__global__ __launch_bounds__(256) void pa_scatter(
    const int* __restrict__ src, const int* __restrict__ dst,
    const int* __restrict__ bases_tbl, int2* __restrict__ bpair, int nblk_a,
    int nbuck, int E) {
  __shared__ int cur[MAXB];
  const int tid = threadIdx.x;
  for (int i = tid; i < nbuck; i += 256)
    cur[i] = bases_tbl[(size_t)i * nblk_a + blockIdx.x];
  __syncthreads();
  const int e0 = blockIdx.x * PA_TILE + tid * PA_EPT;
  if (e0 + PA_EPT <= E) {
#pragma unroll
    for (int i = 0; i < PA_EPT / 4; ++i) {
      const int4 sv = *(const int4*)(src + e0 + i * 4);
      const int4 dv = *(const int4*)(dst + e0 + i * 4);
      const int p0 = atomicAdd(&cur[sv.x >> BSH], 1);
      const int p1 = atomicAdd(&cur[sv.y >> BSH], 1);
      const int p2 = atomicAdd(&cur[sv.z >> BSH], 1);
      const int p3 = atomicAdd(&cur[sv.w >> BSH], 1);
      bpair[p0] = make_int2(sv.x, dv.x);
      bpair[p1] = make_int2(sv.y, dv.y);
      bpair[p2] = make_int2(sv.z, dv.z);
      bpair[p3] = make_int2(sv.w, dv.w);
    }
  } else {
    for (int e = e0; e < E; ++e) {
      const int sv = src[e];
      const int dv = dst[e];
      const int p = atomicAdd(&cur[sv >> BSH], 1);
      bpair[p] = make_int2(sv, dv);
    }
  }
}

// ---------------------------------------------------------------------------
// Fused bucket aggregate: one block per bucket (256 nodes). Full fp32
// accumulator tile (256x64 = 64KB) + denominators live in LDS; edges of the
// bucket are consumed directly from bpair (no dst_sorted, no offs, no
// second sorting pass). ds_add_f32 accumulation rides the LDS pipe, leaving
// VALU for unpack+mul. Epilogue: self-loop + normalize + coalesced store.
// ---------------------------------------------------------------------------
__global__ __launch_bounds__(512) void bucket_aggregate(
    const int2* __restrict__ bpair, const int* __restrict__ bases_tbl,
    const uint* __restrict__ hbp, const float* __restrict__ s,
    const float* __restrict__ t, float* __restrict__ out, int n_nodes,
    int nblk_a, int nbuck, int E) {
  __shared__ float acc[NPB * 64];  // 64KB
  __shared__ float den[NPB];
  __shared__ float w0s[NPB];
  __shared__ int2 stage[8][64];

  const int b = blockIdx.x;
  const int tid = threadIdx.x;
  const int wv = tid >> 6;
  const int lane = tid & 63;
  const int half = lane >> 5;
  const int ch2 = lane & 31;
  const int bstart = bases_tbl[(size_t)b * nblk_a];
  const int bend = (b + 1 < nbuck) ? bases_tbl[(size_t)(b + 1) * nblk_a] : E;
  const int nbase = b << BSH;

  for (int i = tid; i < NPB * 64; i += 512) acc[i] = 0.f;
  for (int i = tid; i < NPB; i += 512) den[i] = 0.f;
  __syncthreads();

  // Edge loop: each wave takes 64-edge batches, strided by 8 waves.
  for (int base = bstart + wv * 64; base < bend; base += 8 * 64) {
    const int myend = min(base + 64, bend);
    const int cnt = myend - base;
    // Stage: lane j -> edge base+j: pack (node_local<<17 | v), w. Pad w=0.
    const int j = base + lane;
    const int idx = j < myend ? j : myend - 1;
    const int2 pr = bpair[idx];
    const float z = s[pr.x] + t[pr.y];
    float w = lrelu_exp(z);
    const int nl = pr.x - nbase;
    if (j < myend)
      atomicAdd(&den[nl], w);
    else
      w = 0.f;
    stage[wv][lane] = make_int2(pr.y | (nl << 17), __float_as_int(w));

    const int npad = min((cnt + 15) & ~15, 64);
    for (int q0 = 0; q0 < npad; q0 += 16) {
      int pk[8];
      float wj[8];
#pragma unroll
      for (int q = 0; q < 8; ++q) {
        const int2 evw = stage[wv][q0 + 8 * half + q];
        pk[q] = evw.x;
        wj[q] = __int_as_float(evw.y);
      }
      uint p[8];
#pragma unroll
      for (int q = 0; q < 8; ++q)
        p[q] = hbp[(size_t)(pk[q] & 0x1ffff) * 32 + ch2];
#pragma unroll
      for (int q = 0; q < 8; ++q) {
        const int arow = (pk[q] >> 17) << 6;
        atomicAdd(&acc[arow + (ch2 << 1)], wj[q] * __uint_as_float(p[q] << 16));
        atomicAdd(&acc[arow + (ch2 << 1) + 1],
                  wj[q] * __uint_as_float(p[q] & 0xffff0000u));
      }
    }
  }
  __syncthreads();

  // Self-loop weight + inverse denominator per node.
  for (int i = tid; i < NPB; i += 512) {
    const int node = nbase + i;
    if (node < n_nodes) {
      const float w0 = lrelu_exp(s[node] + t[node]);
      w0s[i] = w0;
      den[i] = 1.f / (den[i] + w0);
    }
  }
  __syncthreads();

  // Epilogue: out = (acc + w0*h_self) * dinv; coalesced float2 stores.
  for (int i = tid; i < NPB * 32; i += 512) {
    const int nl = i >> 5;
    const int c2 = i & 31;
    const int node = nbase + nl;
    if (node < n_nodes) {
      const uint p = hbp[(size_t)node * 32 + c2];
      const float w0 = w0s[nl];
      const float dinv = den[nl];
      float2 o;
      o.x = (acc[(nl << 6) + (c2 << 1)] + w0 * __uint_as_float(p << 16)) * dinv;
      o.y = (acc[(nl << 6) + (c2 << 1) + 1] +
             w0 * __uint_as_float(p & 0xffff0000u)) *
            dinv;
      *(float2*)&out[(size_t)node * OUT_C + c2 * 2] = o;
    }
  }
}

extern "C" void kernel_launch(void* const* d_in, const int* in_sizes, int n_in,
                              void* d_out, int out_size, void* d_ws,
                              size_t ws_size, hipStream_t stream) {
  const float* x = (const float*)d_in[0];
  const float* W = (const float*)d_in[1];
  const float* a = (const float*)d_in[2];
  const int* edge_index = (const int*)d_in[3];

  const int n_nodes = in_sizes[0] / IN_C;
  const int E = in_sizes[3] / 2;
  const int* src = edge_index;
  const int* dst = edge_index + E;

  float* out = (float*)d_out;

  const int nbuck = (n_nodes + NPB - 1) >> BSH;            // 391
  const int nblk_a = (E + PA_TILE - 1) / PA_TILE;          // 196
  const int tbl_n = nbuck * nblk_a;                        // ~76.6k
  const int n_scan_blocks = (tbl_n + SCAN_TILE - 1) / SCAN_TILE;

  // Workspace layout (8B-aligned chunks first):
  ushort* hb = (ushort*)d_ws;                          // n*64 bf16 (12.8MB)
  int2* bpair = (int2*)(hb + (size_t)n_nodes * OUT_C); // E int2 (12.8MB)
  float* s = (float*)(bpair + E);                      // n
  float* t = s + n_nodes;                              // n
  int* counts_tbl = (int*)(t + n_nodes);               // nbuck*nblk_a
  int* bases_tbl = counts_tbl + (size_t)tbl_n;         // nbuck*nblk_a
  int* block_sums = bases_tbl + (size_t)tbl_n;         // <=1024

  // h (bf16), s, t via MFMA
  {
    const int n_tiles = (n_nodes + 63) / 64;
    const int grid = n_tiles < 512 ? n_tiles : 512;
    gemm_st_kernel<<<grid, 256, 0, stream>>>(x, W, a, hb, s, t, n_nodes,
                                             n_tiles);
  }

  // Atomic-free bucket partition of edges
  pa_count<<<nblk_a, 256, 0, stream>>>(src, counts_tbl, nblk_a, nbuck, E);
  scan_partial<<<n_scan_blocks, SCAN_BLOCK, 0, stream>>>(counts_tbl,
                                                         block_sums, tbl_n);
  scan_blocksums<<<1, 1024, 0, stream>>>(block_sums, n_scan_blocks);
  scan_final_plain<<<n_scan_blocks, SCAN_BLOCK, 0, stream>>>(
      counts_tbl, block_sums, bases_tbl, tbl_n);
  pa_scatter<<<nblk_a, 256, 0, stream>>>(src, dst, bases_tbl, bpair, nblk_a,
                                         nbuck, E);

  // Fused aggregate + normalize (one block per bucket; LDS accumulators)
  bucket_aggregate<<<nbuck, 512, 0, stream>>>(bpair, bases_tbl,
                                              (const uint*)hb, s, t, out,
                                              n_nodes, nblk_a, nbuck, E);
}